// Round 12
// baseline (269.623 us; speedup 1.0000x reference)
//
#include <hip/hip_runtime.h>
#include <hip/hip_bf16.h>
#include <math.h>

#define L_SZ 1024
#define DM   512
#define DI   1024
#define NS   16
#define CH   256

typedef float4 f4;
typedef __attribute__((ext_vector_type(8))) short short8;
typedef __attribute__((ext_vector_type(8))) unsigned short u16x8;
typedef __attribute__((ext_vector_type(4))) float f32x4;

__device__ __forceinline__ float bf2f(ushort u) {
    union { unsigned int i; float f; } x; x.i = ((unsigned int)u) << 16; return x.f;
}
__device__ __forceinline__ ushort f2bf(float f) {
    union { float f; unsigned int i; } x; x.f = f;
    unsigned int r = x.i + 0x7FFFu + ((x.i >> 16) & 1u);
    return (ushort)(r >> 16);
}
// packed RNE f32x2 -> bf16x2 (v_cvt_pk_bf16_f32 on gfx950)
__device__ __forceinline__ uint pkbf(float a, float b) {
    union { __hip_bfloat162 h; uint u; } c;
    c.h = __float22bfloat162_rn(make_float2(a, b));
    return c.u;
}

#define GLOAD16(gp, lp) \
  __builtin_amdgcn_global_load_lds((const __attribute__((address_space(1))) void*)(gp), \
                                   (__attribute__((address_space(3))) void*)(lp), 16, 0, 0)

// ------------------------------------------------------------------
// k_prep: ONE dispatch for all setup work.
//  [0,3328):      6 weight casts fp32->bf16 (in_proj weights pre-scaled by ln_g)
//  [3328,5376):   x transpose+cast (both streams)
//  [5376,6400):   per-row colsums sw_j = sum(g*W), bz_j = sum(b*W) (LN fold)
//  6400:          zero p + row-stats + lam counter
// ------------------------------------------------------------------
__global__ __launch_bounds__(256) void k_prep(
    const float* __restrict__ s0, const float* __restrict__ s1,
    const float* __restrict__ s2, const float* __restrict__ s3,
    const float* __restrict__ s4, const float* __restrict__ s5,
    ushort* __restrict__ d0, ushort* __restrict__ d1,
    ushort* __restrict__ d2, ushort* __restrict__ d3,
    ushort* __restrict__ d4, ushort* __restrict__ d5,
    const float* __restrict__ xv, const float* __restrict__ xi,
    ushort* __restrict__ xtv, ushort* __restrict__ xti,
    const float* __restrict__ vg, const float* __restrict__ ig,
    const float* __restrict__ vb, const float* __restrict__ ib,
    float* __restrict__ sgw, float* __restrict__ bz2,
    float* __restrict__ p, unsigned int* __restrict__ cnt)
{
    __shared__ float tile[32][36];
    const int bid = blockIdx.x;
    const int t = threadIdx.x;
    const int lane = t & 63, wv = t >> 6;
    if (bid < 3328) {
        const float* s; ushort* d; int rel; int scale = 0; const float* g = nullptr;
        if      (bid < 128)  { s = s0; d = d0; rel = bid; }
        else if (bid < 256)  { s = s1; d = d1; rel = bid - 128; }
        else if (bid < 1280) { s = s2; d = d2; rel = bid - 256;  scale = 1; g = vg; }
        else if (bid < 2304) { s = s3; d = d3; rel = bid - 1280; scale = 1; g = ig; }
        else if (bid < 2816) { s = s4; d = d4; rel = bid - 2304; }
        else                 { s = s5; d = d5; rel = bid - 2816; }
        const int i = rel * 256 + t;
        f4 v = ((const f4*)s)[i];
        if (scale) {
            const int k4 = (i * 4) & 511;   // k within 512-row of in_proj weight
            f4 gv = *(const f4*)(g + k4);
            v.x *= gv.x; v.y *= gv.y; v.z *= gv.z; v.w *= gv.w;
        }
        ushort4 o;
        o.x = f2bf(v.x); o.y = f2bf(v.y); o.z = f2bf(v.z); o.w = f2bf(v.w);
        ((ushort4*)d)[i] = o;
        return;
    }
    if (bid < 5376) {
        const int rel = bid - 3328;
        const int l0 = (rel & 31) * 32, c0 = ((rel >> 5) & 7) * 32;
        const int z = rel >> 8;
        const int b = z & 3, st = z >> 2;
        const float* x = st ? xi : xv;
        ushort* xt = st ? xti : xtv;
        {
            int cc = t >> 3, ll4 = (t & 7) << 2;
            f4 v = *(const f4*)(x + ((size_t)(b * CH + c0 + cc)) * L_SZ + l0 + ll4);
            tile[cc][ll4 + 0] = v.x; tile[cc][ll4 + 1] = v.y;
            tile[cc][ll4 + 2] = v.z; tile[cc][ll4 + 3] = v.w;
        }
        __syncthreads();
        {
            int ll = t >> 3, cc4 = (t & 7) << 2;
            ushort4 o;
            o.x = f2bf(tile[cc4 + 0][ll]); o.y = f2bf(tile[cc4 + 1][ll]);
            o.z = f2bf(tile[cc4 + 2][ll]); o.w = f2bf(tile[cc4 + 3][ll]);
            *(ushort4*)(xt + ((size_t)(b * L_SZ + l0 + ll)) * CH + c0 + cc4) = o;
        }
        return;
    }
    if (bid < 6400) {
        // colsums for the LN fold: one wave per in_proj output row j
        const int idx = (bid - 5376) * 4 + wv;   // 0..4095
        const int st = idx >> 11, j = idx & 2047;
        const float* wrow = (st ? s3 : s2) + (size_t)j * 512;
        const float* gv = st ? ig : vg;
        const float* bv = st ? ib : vb;
        float sw = 0.f, bz = 0.f;
        #pragma unroll
        for (int u = 0; u < 8; ++u) {
            const int k = lane + u * 64;
            const float wk = wrow[k];
            sw = fmaf(wk, gv[k], sw);
            bz = fmaf(wk, bv[k], bz);
        }
        #pragma unroll
        for (int off = 1; off < 64; off <<= 1) {
            sw += __shfl_xor(sw, off, 64);
            bz += __shfl_xor(bz, off, 64);
        }
        if (lane == 0) {
            sgw[st * 2048 + j] = sw;
            bz2[st * 2048 + j] = bz;
        }
        return;
    }
    // zero block: p (4096 f) + statsV (8192 f) + statsI (8192 f) contiguous
    const f4 z4 = {0.f, 0.f, 0.f, 0.f};
    for (int i = t; i < 5120; i += 256) ((f4*)p)[i] = z4;
    if (t == 0) *cnt = 0u;
}

// ------------------------------------------------------------------
// unified bf16 MFMA GEMM, tiled BM x BN (4 waves 2x2). XOR k-chunk
// swizzle (2-way LDS aliasing = free).
// MODE 0: conv_red (BN+relu -> bf16 seq + fused pool + fused LN row-stats)
// MODE 1: in_proj on raw seq, LN folded into epilogue (xs bf16 / silu bf16)
// MODE 2: out_proj (bf16) | MODE 3: conv_res (BN+gate+residual)
// ------------------------------------------------------------------
template<int MODE, int BM, int BN>
__global__ __launch_bounds__(256) void k_gemm(
    const ushort* __restrict__ A0, const ushort* __restrict__ A1,
    const ushort* __restrict__ B0, const ushort* __restrict__ B1,
    int K,
    float* __restrict__ o0, float* __restrict__ o1,
    ushort* __restrict__ ob0, ushort* __restrict__ ob1,
    ushort* __restrict__ sb0, ushort* __restrict__ sb1,
    const float* __restrict__ pg, const float* __restrict__ pb,
    const float* __restrict__ pm, const float* __restrict__ pv,
    const float* __restrict__ x0, const float* __restrict__ x1,
    const float* __restrict__ gate, float* __restrict__ pp,
    float* __restrict__ q0, float* __restrict__ q1)
{
    constexpr int MT   = BM / 32;
    constexpr int NT   = BN / 32;
    constexpr int ASEG = BM / 16;
    constexpr int NSEG = (BM + BN) / 16;
    constexpr int SPW  = NSEG / 4;
    __shared__ __align__(16) ushort Sl[(BM + BN) * 32];
    const int t = threadIdx.x;
    const int wv = t >> 6, lane = t & 63;
    const int n0 = blockIdx.x * BN, m0 = blockIdx.y * BM;
    const int st = blockIdx.z;
    const ushort* Ap = st ? A1 : A0;
    const ushort* Bp = st ? B1 : B0;
    const int wm = wv >> 1, wn = wv & 1;
    const int lrow = lane & 15, q = lane >> 4;
    f32x4 acc[MT][NT];
    #pragma unroll
    for (int a_ = 0; a_ < MT; ++a_)
        #pragma unroll
        for (int b_ = 0; b_ < NT; ++b_)
            acc[a_][b_] = (f32x4){0.f, 0.f, 0.f, 0.f};
    const int srow = lane >> 2;
    const int skk  = (((lane & 3) ^ ((lane >> 3) & 3)) << 3);
    const int koff = ((q ^ ((lrow >> 1) & 3)) << 3);
    for (int k0 = 0; k0 < K; k0 += 32) {
        #pragma unroll
        for (int s2 = 0; s2 < SPW; ++s2) {
            const int seg = wv * SPW + s2;
            const int grow = (seg < ASEG) ? (m0 + seg * 16 + srow)
                                          : (n0 + (seg - ASEG) * 16 + srow);
            const ushort* src = (seg < ASEG) ? Ap : Bp;
            GLOAD16(src + (size_t)grow * K + k0 + skk, &Sl[seg * 512]);
        }
        __syncthreads();
        short8 af[MT], bfr[NT];
        #pragma unroll
        for (int mt = 0; mt < MT; ++mt)
            af[mt] = *(const short8*)&Sl[(wm * (MT * 16) + mt * 16 + lrow) * 32 + koff];
        #pragma unroll
        for (int nt = 0; nt < NT; ++nt)
            bfr[nt] = *(const short8*)&Sl[(BM + wn * (NT * 16) + nt * 16 + lrow) * 32 + koff];
        #pragma unroll
        for (int mt = 0; mt < MT; ++mt)
            #pragma unroll
            for (int nt = 0; nt < NT; ++nt)
                acc[mt][nt] = __builtin_amdgcn_mfma_f32_16x16x32_bf16(af[mt], bfr[nt], acc[mt][nt], 0, 0, 0);
        __syncthreads();
    }
    // epilogue; D layout: row = q*4 + r, col = lrow [m89-verified]
    if (MODE == 0) {
        ushort* sq = st ? ob1 : ob0;
        float* ss = st ? q1 : q0;        // [ssum 4096][ssq 4096]
        const int b = m0 >> 10;
        float rs[MT * 4], rq[MT * 4];
        #pragma unroll
        for (int i = 0; i < MT * 4; ++i) { rs[i] = 0.f; rq[i] = 0.f; }
        #pragma unroll
        for (int nt = 0; nt < NT; ++nt) {
            const int gn = n0 + wn * (NT * 16) + nt * 16 + lrow;
            const float s  = pg[gn] * rsqrtf(pv[gn] + 1e-5f);
            const float sh = pb[gn] - pm[gn] * s;
            float psum = 0.f;
            #pragma unroll
            for (int mt = 0; mt < MT; ++mt) {
                const int gm = m0 + wm * (MT * 16) + mt * 16 + q * 4;
                float v[4];
                #pragma unroll
                for (int r = 0; r < 4; ++r) {
                    v[r] = fmaxf(fmaf(acc[mt][nt][r], s, sh), 0.f);
                    psum += v[r];
                    rs[mt * 4 + r] += v[r];
                    rq[mt * 4 + r] = fmaf(v[r], v[r], rq[mt * 4 + r]);
                }
                const uint u01 = pkbf(v[0], v[1]);
                const uint u23 = pkbf(v[2], v[3]);
                ushort* bp = sq + (size_t)gm * DM + gn;
                bp[0]      = (ushort)u01;
                bp[DM]     = (ushort)(u01 >> 16);
                bp[2 * DM] = (ushort)u23;
                bp[3 * DM] = (ushort)(u23 >> 16);
            }
            psum += __shfl_xor(psum, 16, 64);
            psum += __shfl_xor(psum, 32, 64);
            if (q == 0)
                atomicAdd(pp + (b * 1024 + st * 512 + gn), psum * (1.0f / 1024.0f));
        }
        // per-row LN stats: reduce this wave's 32 cols across the 16 lrow lanes
        #pragma unroll
        for (int i = 0; i < MT * 4; ++i) {
            float s1 = rs[i], s2 = rq[i];
            #pragma unroll
            for (int off = 1; off < 16; off <<= 1) {
                s1 += __shfl_xor(s1, off, 64);
                s2 += __shfl_xor(s2, off, 64);
            }
            rs[i] = s1; rq[i] = s2;
        }
        if (lrow == 0) {
            #pragma unroll
            for (int mt = 0; mt < MT; ++mt) {
                const int gm = m0 + wm * (MT * 16) + mt * 16 + q * 4;
                #pragma unroll
                for (int r = 0; r < 4; ++r) {
                    atomicAdd(ss + gm + r, rs[mt * 4 + r]);
                    atomicAdd(ss + 4096 + gm + r, rq[mt * 4 + r]);
                }
            }
        }
    } else if (MODE == 1) {
        // LN folded: val = rstd*(acc - mu*sw[j]) + bz[j]
        const float* ss = st ? pb : pg;          // row stats [ssum][ssq]
        const float* sw = pm + st * 2048;
        const float* bz = pv + st * 2048;
        float mus[MT * 4], rss[MT * 4];
        #pragma unroll
        for (int mt = 0; mt < MT; ++mt)
            #pragma unroll
            for (int r = 0; r < 4; ++r) {
                const int row = m0 + wm * (MT * 16) + mt * 16 + q * 4 + r;
                const float mu = ss[row] * (1.f / 512.f);
                const float var = ss[4096 + row] * (1.f / 512.f) - mu * mu;
                mus[mt * 4 + r] = mu;
                rss[mt * 4 + r] = rsqrtf(var + 1e-5f);
            }
        const bool isx = (n0 < 1024);
        ushort* xp = st ? ob1 : ob0;
        ushort* sp = st ? sb1 : sb0;
        #pragma unroll
        for (int nt = 0; nt < NT; ++nt) {
            const int gn = n0 + wn * (NT * 16) + nt * 16 + lrow;
            const float swn = sw[gn];
            const float bzn = bz[gn];
            #pragma unroll
            for (int mt = 0; mt < MT; ++mt) {
                const int gm = m0 + wm * (MT * 16) + mt * 16 + q * 4;
                float vv[4];
                #pragma unroll
                for (int r = 0; r < 4; ++r)
                    vv[r] = fmaf(rss[mt * 4 + r],
                                 acc[mt][nt][r] - mus[mt * 4 + r] * swn, bzn);
                if (isx) {
                    const uint u01 = pkbf(vv[0], vv[1]);
                    const uint u23 = pkbf(vv[2], vv[3]);
                    ushort* bp = xp + (size_t)gm * DI + gn;
                    bp[0]      = (ushort)u01;
                    bp[DI]     = (ushort)(u01 >> 16);
                    bp[2 * DI] = (ushort)u23;
                    bp[3 * DI] = (ushort)(u23 >> 16);
                } else {
                    #pragma unroll
                    for (int r = 0; r < 4; ++r)
                        vv[r] = vv[r] / (1.f + __expf(-vv[r]));
                    const uint u01 = pkbf(vv[0], vv[1]);
                    const uint u23 = pkbf(vv[2], vv[3]);
                    ushort* bp = sp + (size_t)gm * DI + gn - 1024;
                    bp[0]      = (ushort)u01;
                    bp[DI]     = (ushort)(u01 >> 16);
                    bp[2 * DI] = (ushort)u23;
                    bp[3 * DI] = (ushort)(u23 >> 16);
                }
            }
        }
    } else if (MODE == 2) {
        ushort* fp_ = st ? ob1 : ob0;
        #pragma unroll
        for (int nt = 0; nt < NT; ++nt) {
            const int gn = n0 + wn * (NT * 16) + nt * 16 + lrow;
            #pragma unroll
            for (int mt = 0; mt < MT; ++mt) {
                const int gm = m0 + wm * (MT * 16) + mt * 16 + q * 4;
                const uint u01 = pkbf(acc[mt][nt][0], acc[mt][nt][1]);
                const uint u23 = pkbf(acc[mt][nt][2], acc[mt][nt][3]);
                ushort* bp = fp_ + (size_t)gm * DM + gn;
                bp[0]      = (ushort)u01;
                bp[DM]     = (ushort)(u01 >> 16);
                bp[2 * DM] = (ushort)u23;
                bp[3 * DM] = (ushort)(u23 >> 16);
            }
        }
    } else {  // MODE 3
        const float* xin = st ? x1 : x0;
        float* op = st ? o1 : o0;
        const float g = 1.f / (1.f + __expf(-gate[0]));
        #pragma unroll
        for (int nt = 0; nt < NT; ++nt) {
            const int gn = n0 + wn * (NT * 16) + nt * 16 + lrow;   // channel c
            const float s  = pg[gn] * rsqrtf(pv[gn] + 1e-5f);
            const float sh = pb[gn] - pm[gn] * s;
            #pragma unroll
            for (int mt = 0; mt < MT; ++mt) {
                const int gmb = m0 + wm * (MT * 16) + mt * 16 + q * 4;
                const int b = gmb >> 10, l = gmb & 1023;
                const size_t off = ((size_t)(b * CH + gn)) * L_SZ + l;
                f4 xi = *(const f4*)(xin + off);
                f4 o;
                o.x = xi.x + g * fmaf(acc[mt][nt][0], s, sh);
                o.y = xi.y + g * fmaf(acc[mt][nt][1], s, sh);
                o.z = xi.z + g * fmaf(acc[mt][nt][2], s, sh);
                o.w = xi.w + g * fmaf(acc[mt][nt][3], s, sh);
                *(f4*)(op + off) = o;
            }
        }
    }
}

// ------------------------------------------------------------------
// lam MLP, single kernel (last-block-finishes).
// ------------------------------------------------------------------
__global__ __launch_bounds__(256) void k_lam(
    const float* __restrict__ p, const float* __restrict__ w1,
    const float* __restrict__ b1, const float* __restrict__ w2,
    const float* __restrict__ b2, float* __restrict__ h1,
    float* __restrict__ lam, unsigned int* __restrict__ cnt)
{
    __shared__ float lsm[8];
    __shared__ unsigned int tick;
    const int t = threadIdx.x, lane = t & 63, wv = t >> 6;
    const int idx = blockIdx.x * 4 + wv;    // 0..511
    const int b = idx >> 7, j = idx & 127;
    const float* pb = p + b * 1024;
    const float* wr = w1 + j * 1024;
    float s = 0.f;
    #pragma unroll
    for (int k = 0; k < 16; ++k)
        s = fmaf(pb[lane + k * 64], wr[lane + k * 64], s);
    #pragma unroll
    for (int off = 1; off < 64; off <<= 1) s += __shfl_xor(s, off, 64);
    if (lane == 0) h1[idx] = fmaxf(s + b1[j], 0.f);
    __threadfence();
    __syncthreads();
    if (t == 0) tick = atomicAdd(cnt, 1u);
    __syncthreads();
    if (tick != 127u) return;
    __threadfence();
    {
        const int g32 = t >> 5, l32 = t & 31;
        const int bb = g32 >> 1, kk = g32 & 1;
        const float* hb = h1 + bb * 128;
        const float* wr2 = w2 + kk * 128;
        float ss = 0.f;
        #pragma unroll
        for (int u = 0; u < 4; ++u)
            ss = fmaf(hb[l32 + u * 32], wr2[l32 + u * 32], ss);
        #pragma unroll
        for (int off = 1; off < 32; off <<= 1) ss += __shfl_xor(ss, off, 64);
        if (l32 == 0) lsm[g32] = ss + b2[kk];
    }
    __syncthreads();
    if (t < 4) {
        const float a0 = lsm[t * 2], a1 = lsm[t * 2 + 1];
        const float m  = fmaxf(a0, a1);
        const float e0 = __expf(a0 - m), e1 = __expf(a1 - m);
        const float inv = 1.f / (e0 + e1);
        lam[t * 2 + 0] = e0 * inv;
        lam[t * 2 + 1] = e1 * inv;
    }
}

// ------------------------------------------------------------------
// SSM scan v7: fused bidirectional, 64-row chunks (unchanged from R11).
// ------------------------------------------------------------------
__global__ __launch_bounds__(256) void k_scan(
    const ushort* __restrict__ xsV, const ushort* __restrict__ xsI,
    const ushort* __restrict__ sgV, const ushort* __restrict__ sgI,
    const float* __restrict__ VA, const float* __restrict__ VB,
    const float* __restrict__ VC, const float* __restrict__ IA,
    const float* __restrict__ IB, const float* __restrict__ IC,
    const float* __restrict__ lam,
    ushort* __restrict__ yV, ushort* __restrict__ yI)
{
    __shared__ __align__(16) ushort xf[2][16][128];
    __shared__ __align__(16) ushort xb[2][16][128];
    __shared__ ushort yfb[32][128];
    __shared__ ushort ybb[32][128];
    const int t = threadIdx.x;
    const int shalf = t & 1;
    const int il = t >> 1;
    const int b = blockIdx.y;
    const int st = blockIdx.z >> 4, j = blockIdx.z & 15;
    const ushort* xrow  = (st ? xsI : xsV) + (size_t)b * L_SZ * DI + blockIdx.x * 128;
    const ushort* sgrow = (st ? sgI : sgV) + (size_t)b * L_SZ * DI + blockIdx.x * 128;
    ushort* yrow        = (st ? yI  : yV ) + (size_t)b * L_SZ * DI + blockIdx.x * 128;
    const float* Alog = st ? IA : VA;
    const float* Cm   = st ? IC : VC;
    const float* Bown = st ? IB : VB;
    const float* Both = st ? VB : IB;
    const float lam0 = lam[b * 2 + 0], lam1 = lam[b * 2 + 1];
    float a[8], w[8], gf[8], gb[8];
    const int base = (blockIdx.x * 128 + il) * NS + shalf * 8;
    #pragma unroll
    for (int s = 0; s < 8; ++s) {
        a[s] = fminf(fmaxf(-__expf(Alog[base + s]), -10.f), -0.01f);
        w[s] = 0.5f * Cm[base + s] * fmaf(lam0, Bown[base + s], lam1 * Both[base + s]);
        gf[s] = 0.f; gb[s] = 0.f;
    }
    const int row0 = j << 6;
    const int srow = t >> 4;
    const int scol = (t & 15) << 3;
    {
        int rf = row0 - 64 + srow;          rf = max(0, min(1023, rf));
        GLOAD16(xrow + (size_t)rf * DI + scol, &xf[0][srow][0]);
        int rb = row0 + 127 - srow;         rb = max(0, min(1023, rb));
        GLOAD16(xrow + (size_t)rb * DI + scol, &xb[0][srow][0]);
    }
    __syncthreads();
    for (int si = 0; si < 8; ++si) {
        const int buf = si & 1;
        if (si < 7) {
            const int base2 = (si + 1) * 16;
            int rf = row0 - 64 + base2 + srow;  rf = max(0, min(1023, rf));
            GLOAD16(xrow + (size_t)rf * DI + scol, &xf[buf ^ 1][srow][0]);
            int rb = row0 + 127 - base2 - srow; rb = max(0, min(1023, rb));
            GLOAD16(xrow + (size_t)rb * DI + scol, &xb[buf ^ 1][srow][0]);
        }
        if (si == 4) {
            if (j == 0) {
                for (int s = 0; s < 8; ++s) gf[s] = 0.f;
            }
            if (j == 15) {
                for (int s = 0; s < 8; ++s) gb[s] = 0.f;
            }
        }
        if (si < 4) {
            #pragma unroll
            for (int n = 0; n < 16; ++n) {
                const float vf = bf2f(xf[buf][n][il]);
                const float vb = bf2f(xb[buf][n][il]);
                #pragma unroll
                for (int s = 0; s < 8; ++s) {
                    gf[s] = fmaf(a[s], gf[s], vf);
                    gb[s] = fmaf(a[s], gb[s], vb);
                }
            }
        } else if (si < 6) {
            const int mb = (si - 4) * 16;
            #pragma unroll
            for (int n = 0; n < 16; ++n) {
                const float vf = bf2f(xf[buf][n][il]);
                const float vb = bf2f(xb[buf][n][il]);
                float yf = 0.f, yb = 0.f;
                #pragma unroll
                for (int s = 0; s < 8; ++s) {
                    gf[s] = fmaf(a[s], gf[s], vf);
                    yf    = fmaf(gf[s], w[s], yf);
                    gb[s] = fmaf(a[s], gb[s], vb);
                    yb    = fmaf(gb[s], w[s], yb);
                }
                yf += __shfl_xor(yf, 1, 64);
                yb += __shfl_xor(yb, 1, 64);
                if (shalf == 0) {
                    const int m = mb + n;
                    yfb[m][il]      = f2bf(yf);
                    ybb[31 - m][il] = f2bf(yb);
                }
            }
        } else {
            const int mb = (si - 6) * 16 + 32;
            #pragma unroll
            for (int n = 0; n < 16; ++n) {
                const float vf = bf2f(xf[buf][n][il]);
                const float vb = bf2f(xb[buf][n][il]);
                float yf = 0.f, yb = 0.f;
                #pragma unroll
                for (int s = 0; s < 8; ++s) {
                    gf[s] = fmaf(a[s], gf[s], vf);
                    yf    = fmaf(gf[s], w[s], yf);
                    gb[s] = fmaf(a[s], gb[s], vb);
                    yb    = fmaf(gb[s], w[s], yb);
                }
                yf += __shfl_xor(yf, 1, 64);
                yb += __shfl_xor(yb, 1, 64);
                if (shalf == 0) {
                    const int m = mb + n;
                    const int rF = row0 + m;
                    const float zf = (yf + bf2f(ybb[m - 32][il]))
                                   * bf2f(sgrow[(size_t)rF * DI + il]);
                    yrow[(size_t)rF * DI + il] = f2bf(zf);
                    const int rB = row0 + 63 - m;
                    const float zb = (yb + bf2f(yfb[63 - m][il]))
                                   * bf2f(sgrow[(size_t)rB * DI + il]);
                    yrow[(size_t)rB * DI + il] = f2bf(zb);
                }
            }
        }
        __syncthreads();
    }
}

// ------------------------------------------------------------------
extern "C" void kernel_launch(void* const* d_in, const int* in_sizes, int n_in,
                              void* d_out, int out_size, void* d_ws, size_t ws_size,
                              hipStream_t stream)
{
    const float* xV       = (const float*)d_in[0];
    const float* xI       = (const float*)d_in[1];
    const float* convredw = (const float*)d_in[2];
    const float* bnredg   = (const float*)d_in[3];
    const float* bnredb   = (const float*)d_in[4];
    const float* bnredm   = (const float*)d_in[5];
    const float* bnredv   = (const float*)d_in[6];
    const float* convresw = (const float*)d_in[7];
    const float* bnresg   = (const float*)d_in[8];
    const float* bnresb   = (const float*)d_in[9];
    const float* bnresm   = (const float*)d_in[10];
    const float* bnresv   = (const float*)d_in[11];
    const float* lamw1    = (const float*)d_in[12];
    const float* lamb1    = (const float*)d_in[13];
    const float* lamw2    = (const float*)d_in[14];
    const float* lamb2    = (const float*)d_in[15];
    const float* Vinw     = (const float*)d_in[16];
    const float* Voutw    = (const float*)d_in[17];
    const float* VAlog    = (const float*)d_in[18];
    const float* VB       = (const float*)d_in[19];
    const float* VC       = (const float*)d_in[20];
    const float* Vlng     = (const float*)d_in[21];
    const float* Vlnb     = (const float*)d_in[22];
    const float* Iinw     = (const float*)d_in[23];
    const float* Ioutw    = (const float*)d_in[24];
    const float* IAlog    = (const float*)d_in[25];
    const float* IB       = (const float*)d_in[26];
    const float* IC       = (const float*)d_in[27];
    const float* Ilng     = (const float*)d_in[28];
    const float* Ilnb     = (const float*)d_in[29];
    const float* gate     = (const float*)d_in[30];

    char* W = (char*)d_ws;
    const size_t MB = 1048576;
    ushort* seqV  = (ushort*)(W + 0);            // 4 MB bf16 (4096,512)
    ushort* seqI  = (ushort*)(W + 4  * MB);      // 4 MB
    float*  p     = (float*)(W + 8 * MB);        // 16 KB (pool), then stats
    float*  statsV = (float*)(W + 8 * MB + 16384);   // 32 KB [ssum][ssq]
    float*  statsI = (float*)(W + 8 * MB + 49152);   // 32 KB
    float*  sgWb  = (float*)(W + 8 * MB + 81920);    // 16 KB [V 2048][I 2048]
    float*  bz2b  = (float*)(W + 8 * MB + 98304);    // 16 KB
    float*  lam   = (float*)(W + 8 * MB + 114688);
    float*  h1    = (float*)(W + 8 * MB + 118784);
    unsigned int* cnt = (unsigned int*)(W + 8 * MB + 122880);
    ushort* sgV   = (ushort*)(W + 17 * MB);      // 8 MB bf16 (4096,1024)
    ushort* sgI   = (ushort*)(W + 25 * MB);
    ushort* yV    = (ushort*)(W + 33 * MB);      // 8 MB bf16 (4096,1024)
    ushort* yI    = (ushort*)(W + 41 * MB);
    ushort* wred  = (ushort*)(W + 65 * MB);      // 256 KB
    ushort* wres  = (ushort*)(W + 65 * MB + 262144);
    ushort* winV  = (ushort*)(W + 66 * MB);      // 2 MB (pre-scaled by ln_g)
    ushort* winI  = (ushort*)(W + 68 * MB);
    ushort* woutV = (ushort*)(W + 70 * MB);      // 1 MB
    ushort* woutI = (ushort*)(W + 71 * MB);
    ushort* xtV   = (ushort*)(W + 72 * MB);      // 2 MB
    ushort* xtI   = (ushort*)(W + 74 * MB);
    ushort* xsV   = (ushort*)(W + 84 * MB);      // 8 MB bf16 (4096,1024)
    ushort* xsI   = (ushort*)(W + 92 * MB);      // top = 100 MB
    ushort* featV = seqV;                        // feat overlays seq
    ushort* featI = seqI;
    float*  outp  = (float*)d_out;

    // prep: weight casts (+ln_g scale), x transpose, colsums, zero p/stats/cnt
    k_prep<<<dim3(6401), 256, 0, stream>>>(
        convredw, convresw, Vinw, Iinw, Voutw, Ioutw,
        wred, wres, winV, winI, woutV, woutI,
        xV, xI, xtV, xtI,
        Vlng, Ilng, Vlnb, Ilnb, sgWb, bz2b, p, cnt);
    // conv_red (MFMA, 128x64) -> seq bf16 + fused pool + fused LN stats
    k_gemm<0, 128, 64><<<dim3(8, 32, 2), 256, 0, stream>>>(xtV, xtI, wred, wred, 256,
        nullptr, nullptr, seqV, seqI, nullptr, nullptr,
        bnredg, bnredb, bnredm, bnredv, nullptr, nullptr, nullptr, p,
        statsV, statsI);
    // lambda MLP
    k_lam<<<128, 256, 0, stream>>>(p, lamw1, lamb1, lamw2, lamb2, h1, lam, cnt);
    // in_proj (MFMA, 128x128) on raw seq, LN folded -> xs bf16, sg bf16
    k_gemm<1, 128, 128><<<dim3(16, 32, 2), 256, 0, stream>>>(seqV, seqI, winV, winI, 512,
        nullptr, nullptr, xsV, xsI, sgV, sgI,
        statsV, statsI, sgWb, bz2b, nullptr, nullptr, nullptr, nullptr,
        nullptr, nullptr);
    // fused bidirectional scan v7 -> y bf16
    k_scan<<<dim3(8, 4, 32), 256, 0, stream>>>(xsV, xsI, sgV, sgI,
        VAlog, VB, VC, IAlog, IB, IC, lam, yV, yI);
    // out_proj (MFMA, 128x64) -> feat bf16
    k_gemm<2, 128, 64><<<dim3(8, 32, 2), 256, 0, stream>>>(yV, yI, woutV, woutI, 1024,
        nullptr, nullptr, featV, featI, nullptr, nullptr,
        nullptr, nullptr, nullptr, nullptr, nullptr, nullptr, nullptr, nullptr,
        nullptr, nullptr);
    // conv_res (MFMA, 64x64) + residual -> d_out
    k_gemm<3, 64, 64><<<dim3(4, 64, 2), 256, 0, stream>>>(featV, featI, wres, wres, 512,
        outp, outp + 1048576, nullptr, nullptr, nullptr, nullptr,
        bnresg, bnresb, bnresm, bnresv, xV, xI, gate, nullptr,
        nullptr, nullptr);
}

// Round 13
// 253.325 us; speedup vs baseline: 1.0643x; 1.0643x over previous
//
#include <hip/hip_runtime.h>
#include <hip/hip_bf16.h>
#include <math.h>

#define L_SZ 1024
#define DM   512
#define DI   1024
#define NS   16
#define CH   256

typedef float4 f4;
typedef __attribute__((ext_vector_type(8))) short short8;
typedef __attribute__((ext_vector_type(8))) unsigned short u16x8;
typedef __attribute__((ext_vector_type(4))) float f32x4;

__device__ __forceinline__ float bf2f(ushort u) {
    union { unsigned int i; float f; } x; x.i = ((unsigned int)u) << 16; return x.f;
}
__device__ __forceinline__ ushort f2bf(float f) {
    union { float f; unsigned int i; } x; x.f = f;
    unsigned int r = x.i + 0x7FFFu + ((x.i >> 16) & 1u);
    return (ushort)(r >> 16);
}
// packed RNE f32x2 -> bf16x2 (v_cvt_pk_bf16_f32 on gfx950)
__device__ __forceinline__ uint pkbf(float a, float b) {
    union { __hip_bfloat162 h; uint u; } c;
    c.h = __float22bfloat162_rn(make_float2(a, b));
    return c.u;
}

#define GLOAD16(gp, lp) \
  __builtin_amdgcn_global_load_lds((const __attribute__((address_space(1))) void*)(gp), \
                                   (__attribute__((address_space(3))) void*)(lp), 16, 0, 0)

// ------------------------------------------------------------------
// k_prep: ONE dispatch for all setup work.
//  [0,128):      convredw cast           [128,256):  convresw cast
//  [256,1280):   Vinw cast               [1280,2304): Iinw cast
//  [2304,2816):  Voutw TRANSPOSE+cast -> woTv (1024x512 bf16)
//  [2816,3328):  Ioutw TRANSPOSE+cast -> woTi
//  [3328,5376):  x transpose+cast (both streams)
//  5376:         zero p (4096 f) + lam counter
// ------------------------------------------------------------------
__global__ __launch_bounds__(256) void k_prep(
    const float* __restrict__ s0, const float* __restrict__ s1,
    const float* __restrict__ s2, const float* __restrict__ s3,
    const float* __restrict__ s4, const float* __restrict__ s5,
    ushort* __restrict__ d0, ushort* __restrict__ d1,
    ushort* __restrict__ d2, ushort* __restrict__ d3,
    ushort* __restrict__ d4, ushort* __restrict__ d5,
    const float* __restrict__ xv, const float* __restrict__ xi,
    ushort* __restrict__ xtv, ushort* __restrict__ xti,
    float* __restrict__ p, unsigned int* __restrict__ cnt)
{
    __shared__ float tile[32][36];
    const int bid = blockIdx.x;
    const int t = threadIdx.x;
    if (bid < 2304) {
        const float* s; ushort* d; int rel;
        if      (bid < 128)  { s = s0; d = d0; rel = bid; }
        else if (bid < 256)  { s = s1; d = d1; rel = bid - 128; }
        else if (bid < 1280) { s = s2; d = d2; rel = bid - 256; }
        else                 { s = s3; d = d3; rel = bid - 1280; }
        const int i = rel * 256 + t;
        f4 v = ((const f4*)s)[i];
        ushort4 o;
        o.x = f2bf(v.x); o.y = f2bf(v.y); o.z = f2bf(v.z); o.w = f2bf(v.w);
        ((ushort4*)d)[i] = o;
        return;
    }
    if (bid < 3328) {
        // out_w transpose+cast: (512 d x 1024 k) fp32 -> (1024 k x 512 d) bf16
        const int rel = (bid < 2816) ? bid - 2304 : bid - 2816;
        const float* wo = (bid < 2816) ? s4 : s5;
        ushort* wt      = (bid < 2816) ? d4 : d5;
        const int kt = rel & 31, dt = rel >> 5;
        const int d0_ = dt * 32, k0 = kt * 32;
        {
            int cc = t >> 3, ll4 = (t & 7) << 2;
            f4 v = *(const f4*)(wo + (size_t)(d0_ + cc) * 1024 + k0 + ll4);
            tile[cc][ll4 + 0] = v.x; tile[cc][ll4 + 1] = v.y;
            tile[cc][ll4 + 2] = v.z; tile[cc][ll4 + 3] = v.w;
        }
        __syncthreads();
        {
            int ll = t >> 3, cc4 = (t & 7) << 2;
            ushort4 o;
            o.x = f2bf(tile[cc4 + 0][ll]); o.y = f2bf(tile[cc4 + 1][ll]);
            o.z = f2bf(tile[cc4 + 2][ll]); o.w = f2bf(tile[cc4 + 3][ll]);
            *(ushort4*)(wt + (size_t)(k0 + ll) * 512 + d0_ + cc4) = o;
        }
        return;
    }
    if (bid < 5376) {
        const int rel = bid - 3328;
        const int l0 = (rel & 31) * 32, c0 = ((rel >> 5) & 7) * 32;
        const int z = rel >> 8;
        const int b = z & 3, st = z >> 2;
        const float* x = st ? xi : xv;
        ushort* xt = st ? xti : xtv;
        {
            int cc = t >> 3, ll4 = (t & 7) << 2;
            f4 v = *(const f4*)(x + ((size_t)(b * CH + c0 + cc)) * L_SZ + l0 + ll4);
            tile[cc][ll4 + 0] = v.x; tile[cc][ll4 + 1] = v.y;
            tile[cc][ll4 + 2] = v.z; tile[cc][ll4 + 3] = v.w;
        }
        __syncthreads();
        {
            int ll = t >> 3, cc4 = (t & 7) << 2;
            ushort4 o;
            o.x = f2bf(tile[cc4 + 0][ll]); o.y = f2bf(tile[cc4 + 1][ll]);
            o.z = f2bf(tile[cc4 + 2][ll]); o.w = f2bf(tile[cc4 + 3][ll]);
            *(ushort4*)(xt + ((size_t)(b * L_SZ + l0 + ll)) * CH + c0 + cc4) = o;
        }
        return;
    }
    const f4 z4 = {0.f, 0.f, 0.f, 0.f};
    ((f4*)p)[t]       = z4;
    ((f4*)p)[t + 256] = z4;
    ((f4*)p)[t + 512] = z4;
    ((f4*)p)[t + 768] = z4;
    if (t == 0) *cnt = 0u;
}

// ------------------------------------------------------------------
// unified bf16 MFMA GEMM, tiled BM x BN (4 waves 2x2). XOR k-chunk
// swizzle (2-way LDS aliasing = free).
// MODE 0: conv_red (BN+relu -> bf16 seq + fused pool atomics)
// MODE 1: in_proj (xs bf16 / silu bf16)
// MODE 2: plain bf16 store, row stride OS (used for wcomb precompute)
// MODE 3: fused out: BN+gate+residual, transposed f4 store (K=1024, wcomb)
// ------------------------------------------------------------------
template<int MODE, int BM, int BN, int OS>
__global__ __launch_bounds__(256) void k_gemm(
    const ushort* __restrict__ A0, const ushort* __restrict__ A1,
    const ushort* __restrict__ B0, const ushort* __restrict__ B1,
    int K,
    float* __restrict__ o0, float* __restrict__ o1,
    ushort* __restrict__ ob0, ushort* __restrict__ ob1,
    ushort* __restrict__ sb0, ushort* __restrict__ sb1,
    const float* __restrict__ pg, const float* __restrict__ pb,
    const float* __restrict__ pm, const float* __restrict__ pv,
    const float* __restrict__ x0, const float* __restrict__ x1,
    const float* __restrict__ gate, float* __restrict__ pp)
{
    constexpr int MT   = BM / 32;
    constexpr int NT   = BN / 32;
    constexpr int ASEG = BM / 16;
    constexpr int NSEG = (BM + BN) / 16;
    constexpr int SPW  = NSEG / 4;
    __shared__ __align__(16) ushort Sl[(BM + BN) * 32];
    const int t = threadIdx.x;
    const int wv = t >> 6, lane = t & 63;
    const int n0 = blockIdx.x * BN, m0 = blockIdx.y * BM;
    const int st = blockIdx.z;
    const ushort* Ap = st ? A1 : A0;
    const ushort* Bp = st ? B1 : B0;
    const int wm = wv >> 1, wn = wv & 1;
    const int lrow = lane & 15, q = lane >> 4;
    f32x4 acc[MT][NT];
    #pragma unroll
    for (int a_ = 0; a_ < MT; ++a_)
        #pragma unroll
        for (int b_ = 0; b_ < NT; ++b_)
            acc[a_][b_] = (f32x4){0.f, 0.f, 0.f, 0.f};
    const int srow = lane >> 2;
    const int skk  = (((lane & 3) ^ ((lane >> 3) & 3)) << 3);
    const int koff = ((q ^ ((lrow >> 1) & 3)) << 3);
    for (int k0 = 0; k0 < K; k0 += 32) {
        #pragma unroll
        for (int s2 = 0; s2 < SPW; ++s2) {
            const int seg = wv * SPW + s2;
            const int grow = (seg < ASEG) ? (m0 + seg * 16 + srow)
                                          : (n0 + (seg - ASEG) * 16 + srow);
            const ushort* src = (seg < ASEG) ? Ap : Bp;
            GLOAD16(src + (size_t)grow * K + k0 + skk, &Sl[seg * 512]);
        }
        __syncthreads();
        short8 af[MT], bfr[NT];
        #pragma unroll
        for (int mt = 0; mt < MT; ++mt)
            af[mt] = *(const short8*)&Sl[(wm * (MT * 16) + mt * 16 + lrow) * 32 + koff];
        #pragma unroll
        for (int nt = 0; nt < NT; ++nt)
            bfr[nt] = *(const short8*)&Sl[(BM + wn * (NT * 16) + nt * 16 + lrow) * 32 + koff];
        #pragma unroll
        for (int mt = 0; mt < MT; ++mt)
            #pragma unroll
            for (int nt = 0; nt < NT; ++nt)
                acc[mt][nt] = __builtin_amdgcn_mfma_f32_16x16x32_bf16(af[mt], bfr[nt], acc[mt][nt], 0, 0, 0);
        __syncthreads();
    }
    // epilogue; D layout: row = q*4 + r, col = lrow [m89-verified]
    if (MODE == 0) {
        ushort* sq = st ? ob1 : ob0;
        const int b = m0 >> 10;
        #pragma unroll
        for (int nt = 0; nt < NT; ++nt) {
            const int gn = n0 + wn * (NT * 16) + nt * 16 + lrow;
            const float s  = pg[gn] * rsqrtf(pv[gn] + 1e-5f);
            const float sh = pb[gn] - pm[gn] * s;
            float psum = 0.f;
            #pragma unroll
            for (int mt = 0; mt < MT; ++mt) {
                const int gm = m0 + wm * (MT * 16) + mt * 16 + q * 4;
                float v[4];
                #pragma unroll
                for (int r = 0; r < 4; ++r) {
                    v[r] = fmaxf(fmaf(acc[mt][nt][r], s, sh), 0.f);
                    psum += v[r];
                }
                const uint u01 = pkbf(v[0], v[1]);
                const uint u23 = pkbf(v[2], v[3]);
                ushort* bp = sq + (size_t)gm * DM + gn;
                bp[0]      = (ushort)u01;
                bp[DM]     = (ushort)(u01 >> 16);
                bp[2 * DM] = (ushort)u23;
                bp[3 * DM] = (ushort)(u23 >> 16);
            }
            psum += __shfl_xor(psum, 16, 64);
            psum += __shfl_xor(psum, 32, 64);
            if (q == 0)
                atomicAdd(pp + (b * 1024 + st * 512 + gn), psum * (1.0f / 1024.0f));
        }
    } else if (MODE == 1) {
        const bool isx = (n0 < 1024);
        ushort* xp = st ? ob1 : ob0;
        ushort* sp = st ? sb1 : sb0;
        #pragma unroll
        for (int nt = 0; nt < NT; ++nt) {
            const int gn = n0 + wn * (NT * 16) + nt * 16 + lrow;
            #pragma unroll
            for (int mt = 0; mt < MT; ++mt) {
                const int gm = m0 + wm * (MT * 16) + mt * 16 + q * 4;
                if (isx) {
                    const uint u01 = pkbf(acc[mt][nt][0], acc[mt][nt][1]);
                    const uint u23 = pkbf(acc[mt][nt][2], acc[mt][nt][3]);
                    ushort* bp = xp + (size_t)gm * DI + gn;
                    bp[0]      = (ushort)u01;
                    bp[DI]     = (ushort)(u01 >> 16);
                    bp[2 * DI] = (ushort)u23;
                    bp[3 * DI] = (ushort)(u23 >> 16);
                } else {
                    float sv[4];
                    #pragma unroll
                    for (int r = 0; r < 4; ++r) {
                        const float v = acc[mt][nt][r];
                        sv[r] = v / (1.f + __expf(-v));
                    }
                    const uint u01 = pkbf(sv[0], sv[1]);
                    const uint u23 = pkbf(sv[2], sv[3]);
                    ushort* bp = sp + (size_t)gm * DI + gn - 1024;
                    bp[0]      = (ushort)u01;
                    bp[DI]     = (ushort)(u01 >> 16);
                    bp[2 * DI] = (ushort)u23;
                    bp[3 * DI] = (ushort)(u23 >> 16);
                }
            }
        }
    } else if (MODE == 2) {
        ushort* fp_ = st ? ob1 : ob0;
        #pragma unroll
        for (int nt = 0; nt < NT; ++nt) {
            const int gn = n0 + wn * (NT * 16) + nt * 16 + lrow;
            #pragma unroll
            for (int mt = 0; mt < MT; ++mt) {
                const int gm = m0 + wm * (MT * 16) + mt * 16 + q * 4;
                const uint u01 = pkbf(acc[mt][nt][0], acc[mt][nt][1]);
                const uint u23 = pkbf(acc[mt][nt][2], acc[mt][nt][3]);
                ushort* bp = fp_ + (size_t)gm * OS + gn;
                bp[0]      = (ushort)u01;
                bp[OS]     = (ushort)(u01 >> 16);
                bp[2 * OS] = (ushort)u23;
                bp[3 * OS] = (ushort)(u23 >> 16);
            }
        }
    } else {  // MODE 3
        const float* xin = st ? x1 : x0;
        float* op = st ? o1 : o0;
        const float g = 1.f / (1.f + __expf(-gate[0]));
        #pragma unroll
        for (int nt = 0; nt < NT; ++nt) {
            const int gn = n0 + wn * (NT * 16) + nt * 16 + lrow;   // channel c
            const float s  = pg[gn] * rsqrtf(pv[gn] + 1e-5f);
            const float sh = pb[gn] - pm[gn] * s;
            #pragma unroll
            for (int mt = 0; mt < MT; ++mt) {
                const int gmb = m0 + wm * (MT * 16) + mt * 16 + q * 4;
                const int b = gmb >> 10, l = gmb & 1023;
                const size_t off = ((size_t)(b * CH + gn)) * L_SZ + l;
                f4 xi = *(const f4*)(xin + off);
                f4 o;
                o.x = xi.x + g * fmaf(acc[mt][nt][0], s, sh);
                o.y = xi.y + g * fmaf(acc[mt][nt][1], s, sh);
                o.z = xi.z + g * fmaf(acc[mt][nt][2], s, sh);
                o.w = xi.w + g * fmaf(acc[mt][nt][3], s, sh);
                *(f4*)(op + off) = o;
            }
        }
    }
}

// ------------------------------------------------------------------
// lam MLP, single kernel (last-block-finishes).
// ------------------------------------------------------------------
__global__ __launch_bounds__(256) void k_lam(
    const float* __restrict__ p, const float* __restrict__ w1,
    const float* __restrict__ b1, const float* __restrict__ w2,
    const float* __restrict__ b2, float* __restrict__ h1,
    float* __restrict__ lam, unsigned int* __restrict__ cnt)
{
    __shared__ float lsm[8];
    __shared__ unsigned int tick;
    const int t = threadIdx.x, lane = t & 63, wv = t >> 6;
    const int idx = blockIdx.x * 4 + wv;    // 0..511
    const int b = idx >> 7, j = idx & 127;
    const float* pb = p + b * 1024;
    const float* wr = w1 + j * 1024;
    float s = 0.f;
    #pragma unroll
    for (int k = 0; k < 16; ++k)
        s = fmaf(pb[lane + k * 64], wr[lane + k * 64], s);
    #pragma unroll
    for (int off = 1; off < 64; off <<= 1) s += __shfl_xor(s, off, 64);
    if (lane == 0) h1[idx] = fmaxf(s + b1[j], 0.f);
    __threadfence();
    __syncthreads();
    if (t == 0) tick = atomicAdd(cnt, 1u);
    __syncthreads();
    if (tick != 127u) return;
    __threadfence();
    {
        const int g32 = t >> 5, l32 = t & 31;
        const int bb = g32 >> 1, kk = g32 & 1;
        const float* hb = h1 + bb * 128;
        const float* wr2 = w2 + kk * 128;
        float ss = 0.f;
        #pragma unroll
        for (int u = 0; u < 4; ++u)
            ss = fmaf(hb[l32 + u * 32], wr2[l32 + u * 32], ss);
        #pragma unroll
        for (int off = 1; off < 32; off <<= 1) ss += __shfl_xor(ss, off, 64);
        if (l32 == 0) lsm[g32] = ss + b2[kk];
    }
    __syncthreads();
    if (t < 4) {
        const float a0 = lsm[t * 2], a1 = lsm[t * 2 + 1];
        const float m  = fmaxf(a0, a1);
        const float e0 = __expf(a0 - m), e1 = __expf(a1 - m);
        const float inv = 1.f / (e0 + e1);
        lam[t * 2 + 0] = e0 * inv;
        lam[t * 2 + 1] = e1 * inv;
    }
}

// ------------------------------------------------------------------
// fused LN + cast, bf16 in/out. One row per wave, 4 rows/block.
// ------------------------------------------------------------------
__global__ __launch_bounds__(256) void k_ln(
    const ushort* __restrict__ seq0, const ushort* __restrict__ seq1,
    const float* __restrict__ g0, const float* __restrict__ b0,
    const float* __restrict__ g1, const float* __restrict__ b1,
    ushort* __restrict__ ln0, ushort* __restrict__ ln1)
{
    const int t = threadIdx.x, lane = t & 63, wv = t >> 6;
    const int row = blockIdx.x * 4 + wv, st = blockIdx.y;
    const ushort* seq = st ? seq1 : seq0;
    const float* gg  = st ? g1 : g0;
    const float* bb  = st ? b1 : b0;
    ushort* ln = st ? ln1 : ln0;
    const u16x8 v = *(const u16x8*)(seq + (size_t)row * DM + lane * 8);
    float f[8];
    float s = 0.f, ss = 0.f;
    #pragma unroll
    for (int i = 0; i < 8; ++i) {
        f[i] = bf2f(v[i]);
        s += f[i];
        ss = fmaf(f[i], f[i], ss);
    }
    #pragma unroll
    for (int off = 1; off < 64; off <<= 1) {
        s += __shfl_xor(s, off, 64); ss += __shfl_xor(ss, off, 64);
    }
    const float mu = s * (1.f / 512.f);
    const float rstd = rsqrtf(ss * (1.f / 512.f) - mu * mu + 1e-5f);
    const f4 gv0 = *(const f4*)(gg + lane * 8);
    const f4 gv1 = *(const f4*)(gg + lane * 8 + 4);
    const f4 bv0 = *(const f4*)(bb + lane * 8);
    const f4 bv1 = *(const f4*)(bb + lane * 8 + 4);
    const float gvv[8] = {gv0.x, gv0.y, gv0.z, gv0.w, gv1.x, gv1.y, gv1.z, gv1.w};
    const float bvv[8] = {bv0.x, bv0.y, bv0.z, bv0.w, bv1.x, bv1.y, bv1.z, bv1.w};
    u16x8 o;
    #pragma unroll
    for (int i = 0; i < 8; i += 2) {
        const uint u = pkbf(fmaf((f[i]     - mu) * rstd, gvv[i],     bvv[i]),
                            fmaf((f[i + 1] - mu) * rstd, gvv[i + 1], bvv[i + 1]));
        o[i]     = (ushort)u;
        o[i + 1] = (ushort)(u >> 16);
    }
    *(u16x8*)(ln + (size_t)row * DM + lane * 8) = o;
}

// ------------------------------------------------------------------
// SSM scan v7: fused bidirectional, 64-row chunks (unchanged from R11).
// ------------------------------------------------------------------
__global__ __launch_bounds__(256) void k_scan(
    const ushort* __restrict__ xsV, const ushort* __restrict__ xsI,
    const ushort* __restrict__ sgV, const ushort* __restrict__ sgI,
    const float* __restrict__ VA, const float* __restrict__ VB,
    const float* __restrict__ VC, const float* __restrict__ IA,
    const float* __restrict__ IB, const float* __restrict__ IC,
    const float* __restrict__ lam,
    ushort* __restrict__ yV, ushort* __restrict__ yI)
{
    __shared__ __align__(16) ushort xf[2][16][128];
    __shared__ __align__(16) ushort xb[2][16][128];
    __shared__ ushort yfb[32][128];
    __shared__ ushort ybb[32][128];
    const int t = threadIdx.x;
    const int shalf = t & 1;
    const int il = t >> 1;
    const int b = blockIdx.y;
    const int st = blockIdx.z >> 4, j = blockIdx.z & 15;
    const ushort* xrow  = (st ? xsI : xsV) + (size_t)b * L_SZ * DI + blockIdx.x * 128;
    const ushort* sgrow = (st ? sgI : sgV) + (size_t)b * L_SZ * DI + blockIdx.x * 128;
    ushort* yrow        = (st ? yI  : yV ) + (size_t)b * L_SZ * DI + blockIdx.x * 128;
    const float* Alog = st ? IA : VA;
    const float* Cm   = st ? IC : VC;
    const float* Bown = st ? IB : VB;
    const float* Both = st ? VB : IB;
    const float lam0 = lam[b * 2 + 0], lam1 = lam[b * 2 + 1];
    float a[8], w[8], gf[8], gb[8];
    const int base = (blockIdx.x * 128 + il) * NS + shalf * 8;
    #pragma unroll
    for (int s = 0; s < 8; ++s) {
        a[s] = fminf(fmaxf(-__expf(Alog[base + s]), -10.f), -0.01f);
        w[s] = 0.5f * Cm[base + s] * fmaf(lam0, Bown[base + s], lam1 * Both[base + s]);
        gf[s] = 0.f; gb[s] = 0.f;
    }
    const int row0 = j << 6;
    const int srow = t >> 4;
    const int scol = (t & 15) << 3;
    {
        int rf = row0 - 64 + srow;          rf = max(0, min(1023, rf));
        GLOAD16(xrow + (size_t)rf * DI + scol, &xf[0][srow][0]);
        int rb = row0 + 127 - srow;         rb = max(0, min(1023, rb));
        GLOAD16(xrow + (size_t)rb * DI + scol, &xb[0][srow][0]);
    }
    __syncthreads();
    for (int si = 0; si < 8; ++si) {
        const int buf = si & 1;
        if (si < 7) {
            const int base2 = (si + 1) * 16;
            int rf = row0 - 64 + base2 + srow;  rf = max(0, min(1023, rf));
            GLOAD16(xrow + (size_t)rf * DI + scol, &xf[buf ^ 1][srow][0]);
            int rb = row0 + 127 - base2 - srow; rb = max(0, min(1023, rb));
            GLOAD16(xrow + (size_t)rb * DI + scol, &xb[buf ^ 1][srow][0]);
        }
        if (si == 4) {
            if (j == 0) {
                for (int s = 0; s < 8; ++s) gf[s] = 0.f;
            }
            if (j == 15) {
                for (int s = 0; s < 8; ++s) gb[s] = 0.f;
            }
        }
        if (si < 4) {
            #pragma unroll
            for (int n = 0; n < 16; ++n) {
                const float vf = bf2f(xf[buf][n][il]);
                const float vb = bf2f(xb[buf][n][il]);
                #pragma unroll
                for (int s = 0; s < 8; ++s) {
                    gf[s] = fmaf(a[s], gf[s], vf);
                    gb[s] = fmaf(a[s], gb[s], vb);
                }
            }
        } else if (si < 6) {
            const int mb = (si - 4) * 16;
            #pragma unroll
            for (int n = 0; n < 16; ++n) {
                const float vf = bf2f(xf[buf][n][il]);
                const float vb = bf2f(xb[buf][n][il]);
                float yf = 0.f, yb = 0.f;
                #pragma unroll
                for (int s = 0; s < 8; ++s) {
                    gf[s] = fmaf(a[s], gf[s], vf);
                    yf    = fmaf(gf[s], w[s], yf);
                    gb[s] = fmaf(a[s], gb[s], vb);
                    yb    = fmaf(gb[s], w[s], yb);
                }
                yf += __shfl_xor(yf, 1, 64);
                yb += __shfl_xor(yb, 1, 64);
                if (shalf == 0) {
                    const int m = mb + n;
                    yfb[m][il]      = f2bf(yf);
                    ybb[31 - m][il] = f2bf(yb);
                }
            }
        } else {
            const int mb = (si - 6) * 16 + 32;
            #pragma unroll
            for (int n = 0; n < 16; ++n) {
                const float vf = bf2f(xf[buf][n][il]);
                const float vb = bf2f(xb[buf][n][il]);
                float yf = 0.f, yb = 0.f;
                #pragma unroll
                for (int s = 0; s < 8; ++s) {
                    gf[s] = fmaf(a[s], gf[s], vf);
                    yf    = fmaf(gf[s], w[s], yf);
                    gb[s] = fmaf(a[s], gb[s], vb);
                    yb    = fmaf(gb[s], w[s], yb);
                }
                yf += __shfl_xor(yf, 1, 64);
                yb += __shfl_xor(yb, 1, 64);
                if (shalf == 0) {
                    const int m = mb + n;
                    const int rF = row0 + m;
                    const float zf = (yf + bf2f(ybb[m - 32][il]))
                                   * bf2f(sgrow[(size_t)rF * DI + il]);
                    yrow[(size_t)rF * DI + il] = f2bf(zf);
                    const int rB = row0 + 63 - m;
                    const float zb = (yb + bf2f(yfb[63 - m][il]))
                                   * bf2f(sgrow[(size_t)rB * DI + il]);
                    yrow[(size_t)rB * DI + il] = f2bf(zb);
                }
            }
        }
        __syncthreads();
    }
}

// ------------------------------------------------------------------
extern "C" void kernel_launch(void* const* d_in, const int* in_sizes, int n_in,
                              void* d_out, int out_size, void* d_ws, size_t ws_size,
                              hipStream_t stream)
{
    const float* xV       = (const float*)d_in[0];
    const float* xI       = (const float*)d_in[1];
    const float* convredw = (const float*)d_in[2];
    const float* bnredg   = (const float*)d_in[3];
    const float* bnredb   = (const float*)d_in[4];
    const float* bnredm   = (const float*)d_in[5];
    const float* bnredv   = (const float*)d_in[6];
    const float* convresw = (const float*)d_in[7];
    const float* bnresg   = (const float*)d_in[8];
    const float* bnresb   = (const float*)d_in[9];
    const float* bnresm   = (const float*)d_in[10];
    const float* bnresv   = (const float*)d_in[11];
    const float* lamw1    = (const float*)d_in[12];
    const float* lamb1    = (const float*)d_in[13];
    const float* lamw2    = (const float*)d_in[14];
    const float* lamb2    = (const float*)d_in[15];
    const float* Vinw     = (const float*)d_in[16];
    const float* Voutw    = (const float*)d_in[17];
    const float* VAlog    = (const float*)d_in[18];
    const float* VB       = (const float*)d_in[19];
    const float* VC       = (const float*)d_in[20];
    const float* Vlng     = (const float*)d_in[21];
    const float* Vlnb     = (const float*)d_in[22];
    const float* Iinw     = (const float*)d_in[23];
    const float* Ioutw    = (const float*)d_in[24];
    const float* IAlog    = (const float*)d_in[25];
    const float* IB       = (const float*)d_in[26];
    const float* IC       = (const float*)d_in[27];
    const float* Ilng     = (const float*)d_in[28];
    const float* Ilnb     = (const float*)d_in[29];
    const float* gate     = (const float*)d_in[30];

    char* W = (char*)d_ws;
    const size_t MB = 1048576;
    ushort* seqV  = (ushort*)(W + 0);            // 4 MB bf16 (4096,512)
    ushort* seqI  = (ushort*)(W + 4  * MB);      // 4 MB
    float*  p     = (float*)(W + 8 * MB);        // 16 KB
    float*  lam   = (float*)(W + 8 * MB + 16384);
    float*  h1    = (float*)(W + 8 * MB + 32768);
    unsigned int* cnt = (unsigned int*)(W + 8 * MB + 49152);
    ushort* sgV   = (ushort*)(W + 17 * MB);      // 8 MB bf16 (4096,1024)
    ushort* sgI   = (ushort*)(W + 25 * MB);
    ushort* yV    = (ushort*)(W + 33 * MB);      // 8 MB bf16 (4096,1024)
    ushort* yI    = (ushort*)(W + 41 * MB);
    ushort* wred  = (ushort*)(W + 65 * MB);      // 256 KB
    ushort* wres  = (ushort*)(W + 65 * MB + 262144);
    ushort* winV  = (ushort*)(W + 66 * MB);      // 2 MB
    ushort* winI  = (ushort*)(W + 68 * MB);
    ushort* woTv  = (ushort*)(W + 70 * MB);      // 1 MB bf16 (1024,512) = Voutw^T
    ushort* woTi  = (ushort*)(W + 71 * MB);      // 1 MB
    ushort* xtV   = (ushort*)(W + 72 * MB);      // 2 MB
    ushort* xtI   = (ushort*)(W + 74 * MB);
    ushort* lnV   = (ushort*)(W + 76 * MB);      // 4 MB
    ushort* lnI   = (ushort*)(W + 80 * MB);
    ushort* xsV   = (ushort*)(W + 84 * MB);      // 8 MB bf16 (4096,1024)
    ushort* xsI   = (ushort*)(W + 92 * MB);
    ushort* wcombV = (ushort*)(W + 100 * MB);    // 512 KB bf16 (256,1024)
    ushort* wcombI = (ushort*)(W + 100 * MB + 524288);   // top = 101 MB
    float*  outp  = (float*)d_out;

    // prep: weight casts + wout transposes + x transpose + zero p/cnt
    k_prep<<<dim3(5377), 256, 0, stream>>>(
        convredw, convresw, Vinw, Iinw, Voutw, Ioutw,
        wred, wres, winV, winI, woTv, woTi,
        xV, xI, xtV, xtI, p, cnt);
    // wcomb[c,k] = sum_d wres[c,d]*wout[d,k]  (256x1024, K=512, bf16 out)
    k_gemm<2, 64, 64, 1024><<<dim3(16, 4, 2), 256, 0, stream>>>(
        wres, wres, woTv, woTi, 512,
        nullptr, nullptr, wcombV, wcombI, nullptr, nullptr,
        nullptr, nullptr, nullptr, nullptr, nullptr, nullptr, nullptr, nullptr);
    // conv_red (MFMA, 128x64) -> seq bf16 + fused pool
    k_gemm<0, 128, 64, 512><<<dim3(8, 32, 2), 256, 0, stream>>>(xtV, xtI, wred, wred, 256,
        nullptr, nullptr, seqV, seqI, nullptr, nullptr,
        bnredg, bnredb, bnredm, bnredv, nullptr, nullptr, nullptr, p);
    // lambda MLP (single kernel, last-block finishes)
    k_lam<<<128, 256, 0, stream>>>(p, lamw1, lamb1, lamw2, lamb2, h1, lam, cnt);
    // LN -> bf16
    k_ln<<<dim3(1024, 2), 256, 0, stream>>>(seqV, seqI, Vlng, Vlnb, Ilng, Ilnb, lnV, lnI);
    // in_proj (MFMA, 128x128) -> xs bf16, sg bf16
    k_gemm<1, 128, 128, 512><<<dim3(16, 32, 2), 256, 0, stream>>>(lnV, lnI, winV, winI, 512,
        nullptr, nullptr, xsV, xsI, sgV, sgI,
        nullptr, nullptr, nullptr, nullptr, nullptr, nullptr, nullptr, nullptr);
    // fused bidirectional scan v7 -> y bf16
    k_scan<<<dim3(8, 4, 32), 256, 0, stream>>>(xsV, xsI, sgV, sgI,
        VAlog, VB, VC, IAlog, IB, IC, lam, yV, yI);
    // fused out-proj+conv_res (MFMA, 64x64, K=1024, B=wcomb) + residual -> d_out
    k_gemm<3, 64, 64, 512><<<dim3(4, 64, 2), 256, 0, stream>>>(yV, yI, wcombV, wcombI, 1024,
        outp, outp + 1048576, nullptr, nullptr, nullptr, nullptr,
        bnresg, bnresb, bnresm, bnresv, xV, xI, gate, nullptr);
}